// Round 19
// baseline (700.358 us; speedup 1.0000x reference)
//
#include <hip/hip_runtime.h>
#include <hip/hip_bf16.h>

#define HD 128

typedef __attribute__((ext_vector_type(8))) short short8;
typedef __attribute__((ext_vector_type(4))) float f32x4;
typedef __attribute__((ext_vector_type(4))) unsigned int u32x4;

// fast silu: v * rcp(1+exp(-v))
__device__ __forceinline__ float fast_silu(float v) {
    return v * __builtin_amdgcn_rcpf(1.f + __expf(-v));
}

// RNE f32 pair -> packed bf16x2 via HW cvt
__device__ __forceinline__ unsigned int pk2(float a, float b) {
    __hip_bfloat162 h = __float22bfloat162_rn(float2{a, b});
    unsigned int u;
    __builtin_memcpy(&u, &h, 4);
    return u;
}

__device__ __forceinline__ unsigned short f2bf(float f) {
    unsigned int u = __builtin_bit_cast(unsigned int, f);
    u += 0x7FFFu + ((u >> 16) & 1u);   // RNE
    return (unsigned short)(u >> 16);
}

// pack 8 f32 -> short8 of bf16 (RNE)
__device__ __forceinline__ short8 pack8(f32x4 lo, f32x4 hi) {
    u32x4 p;
    p[0] = pk2(lo[0], lo[1]);
    p[1] = pk2(lo[2], lo[3]);
    p[2] = pk2(hi[0], hi[1]);
    p[3] = pk2(hi[2], hi[3]);
    return __builtin_bit_cast(short8, p);
}

// fixed-point field: 16384 + rint(m*32), clamped, fits [0, 2^15)
__device__ __forceinline__ unsigned long long fpf(float m) {
    int r = (int)rintf(m * 32.f);
    r = r < -16000 ? -16000 : (r > 16000 ? 16000 : r);
    return (unsigned long long)(unsigned)(16384 + r);
}

// ---------------- zero workspace ----------------
__global__ __launch_bounds__(512) void zero_kernel(float* __restrict__ p, int nvec4) {
    int i = blockIdx.x * 512 + threadIdx.x;
    if (i < nvec4) reinterpret_cast<f32x4*>(p)[i] = f32x4{0.f, 0.f, 0.f, 0.f};
}

// Vectorized W1 staging into chunk-major LDS: w1s[c][n][j] = W1[(c*8+j)*128+n].
#define STAGE_W1_VEC(W1, w1s, nthr)                                          \
    for (int i = threadIdx.x; i < (HD * HD / 8); i += (nthr)) {              \
        const int kp = i >> 5, nq = i & 31;                                  \
        const int k0 = kp * 2, n0 = nq * 4;                                  \
        f32x4 ra = *reinterpret_cast<const f32x4*>(W1 + k0 * HD + n0);       \
        f32x4 rb = *reinterpret_cast<const f32x4*>(W1 + (k0 + 1) * HD + n0); \
        _Pragma("unroll")                                                    \
        for (int j = 0; j < 4; ++j) {                                        \
            unsigned int u = pk2(ra[j], rb[j]);                              \
            *reinterpret_cast<unsigned int*>(&w1s[k0 >> 3][n0 + j][k0 & 6]) = u; \
        }                                                                    \
    }

// ---------------- edge kernel (512 thr = 8 waves; VGPR capped for 5 waves/SIMD) --
// R14/R16 schedule: x-issue -> ei-prefetch -> pack A -> GEMM+silu -> consume x
// -> next A-loads -> atomic (youngest vmem op).
// __launch_bounds__(512, 5): cap VGPR ~102 -> 5 waves/SIMD (20 waves/CU) vs 4.
__global__ __launch_bounds__(512, 5) void edge_kernel(
    const float* __restrict__ m_ij, const float* __restrict__ x,
    const int* __restrict__ srci, const int* __restrict__ dsti,
    const float* __restrict__ W1, const float* __restrict__ b1,
    const float* __restrict__ W2, const float* __restrict__ b2,
    unsigned long long* __restrict__ acc8, int E, int ntile_cnt)
{
    __shared__ __align__(16) unsigned short w1s[16][HD][8];   // 32 KB
    __shared__ float b1s[HD], w2s[HD];
    const int tid = threadIdx.x;
    STAGE_W1_VEC(W1, w1s, 512)
    if (tid < HD) { b1s[tid] = b1[tid]; w2s[tid] = W2[tid]; }
    __syncthreads();

    const int lane = tid & 63, wave = tid >> 6;
    const int g = lane >> 4, lm = lane & 15;
    const float b2v = b2[0];
    const bool owner = (lm < 4);

    int tile = blockIdx.x;
    f32x4 araw[8];
    int sc = 0, dc = 0;
    if (tile < ntile_cnt) {
        int ar = tile * 128 + wave * 16 + lm;
        if (ar >= E) ar = E - 1;
        const float* p = m_ij + (size_t)ar * HD + g * 8;
        #pragma unroll
        for (int kk = 0; kk < 4; ++kk) {
            araw[2 * kk]     = *reinterpret_cast<const f32x4*>(p + kk * 32);
            araw[2 * kk + 1] = *reinterpret_cast<const f32x4*>(p + kk * 32 + 4);
        }
        if (owner) {
            int e = tile * 128 + wave * 16 + g * 4 + lm;
            if (e >= E) e = E - 1;
            sc = srci[e]; dc = dsti[e];
        }
    }

    while (tile < ntile_cnt) {
        const int next = tile + gridDim.x;
        const int ecur = tile * 128 + wave * 16 + g * 4 + lm;
        const bool valid = owner && (ecur < E);

        // (1) issue x-loads for CURRENT tile (addresses prefetched)
        float xs0 = 0.f, xs1 = 0.f, xs2 = 0.f, xd0 = 0.f, xd1 = 0.f, xd2 = 0.f;
        if (valid) {
            const float* xs = x + (size_t)sc * 3;
            const float* xd = x + (size_t)dc * 3;
            xs0 = xs[0]; xs1 = xs[1]; xs2 = xs[2];
            xd0 = xd[0]; xd1 = xd[1]; xd2 = xd[2];
        }
        unsigned long long* aptr = valid ? &acc8[dc] : nullptr;

        // (2) prefetch ei for NEXT tile
        int sn = 0, dn = 0;
        if (owner && next < ntile_cnt) {
            int e = next * 128 + wave * 16 + g * 4 + lm;
            if (e >= E) e = E - 1;
            sn = srci[e]; dn = dsti[e];
        }

        // (3) pack A fragments
        short8 afrag[4];
        #pragma unroll
        for (int kk = 0; kk < 4; ++kk)
            afrag[kk] = pack8(araw[2 * kk], araw[2 * kk + 1]);

        // (4) GEMM + fused second layer
        float pr0 = 0.f, pr1 = 0.f, pr2 = 0.f, pr3 = 0.f;
        #pragma unroll
        for (int nt = 0; nt < 8; ++nt) {
            f32x4 acc = {0.f, 0.f, 0.f, 0.f};
            #pragma unroll
            for (int kk = 0; kk < 4; ++kk) {
                short8 bfrag = *reinterpret_cast<const short8*>(&w1s[kk * 4 + g][nt * 16 + lm][0]);
                acc = __builtin_amdgcn_mfma_f32_16x16x32_bf16(afrag[kk], bfrag, acc, 0, 0, 0);
            }
            const int col = nt * 16 + lm;
            const float bb = b1s[col], wv = w2s[col];
            pr0 += fast_silu(acc[0] + bb) * wv;
            pr1 += fast_silu(acc[1] + bb) * wv;
            pr2 += fast_silu(acc[2] + bb) * wv;
            pr3 += fast_silu(acc[3] + bb) * wv;
        }
        pr0 += __shfl_xor(pr0, 1); pr0 += __shfl_xor(pr0, 2); pr0 += __shfl_xor(pr0, 4); pr0 += __shfl_xor(pr0, 8);
        pr1 += __shfl_xor(pr1, 1); pr1 += __shfl_xor(pr1, 2); pr1 += __shfl_xor(pr1, 4); pr1 += __shfl_xor(pr1, 8);
        pr2 += __shfl_xor(pr2, 1); pr2 += __shfl_xor(pr2, 2); pr2 += __shfl_xor(pr2, 4); pr2 += __shfl_xor(pr2, 8);
        pr3 += __shfl_xor(pr3, 1); pr3 += __shfl_xor(pr3, 2); pr3 += __shfl_xor(pr3, 4); pr3 += __shfl_xor(pr3, 8);

        // (5) consume x at end of compute phase, build payload
        unsigned long long addend = 0;
        if (valid) {
            float w = (lm == 0 ? pr0 : lm == 1 ? pr1 : lm == 2 ? pr2 : pr3) + b2v;
            addend = (fpf((xs0 - xd0) * w) << 48) | (fpf((xs1 - xd1) * w) << 32)
                   | (fpf((xs2 - xd2) * w) << 16) | 1ULL;
        }

        // (6) issue next tile's A-loads BEFORE the atomic
        if (next < ntile_cnt) {
            int ar = next * 128 + wave * 16 + lm;
            if (ar >= E) ar = E - 1;
            const float* p = m_ij + (size_t)ar * HD + g * 8;
            #pragma unroll
            for (int kk = 0; kk < 4; ++kk) {
                araw[2 * kk]     = *reinterpret_cast<const f32x4*>(p + kk * 32);
                araw[2 * kk + 1] = *reinterpret_cast<const f32x4*>(p + kk * 32 + 4);
            }
        }

        // (7) atomic last: youngest vmem op in flight
        if (aptr) atomicAdd(aptr, addend);

        sc = sn; dc = dn;
        tile = next;
    }
}

// ---------------- node kernel ----------------
__global__ __launch_bounds__(256) void node_kernel(
    const float* __restrict__ h, const float* __restrict__ vel,
    const float* __restrict__ W1, const float* __restrict__ b1,
    const float* __restrict__ W2, const float* __restrict__ b2,
    const unsigned long long* __restrict__ acc8,
    float* __restrict__ out, int N, int ntile_cnt)
{
    __shared__ __align__(16) unsigned short w1s[16][HD][8];
    __shared__ float b1s[HD], w2s[HD * 5], b2s[5];
    const int tid = threadIdx.x;
    STAGE_W1_VEC(W1, w1s, 256)
    if (tid < HD) b1s[tid] = b1[tid];
    for (int i = tid; i < HD * 5; i += 256) w2s[i] = W2[i];
    if (tid < 5) b2s[tid] = b2[tid];
    __syncthreads();

    const int lane = tid & 63, wave = tid >> 6;
    const int g = lane >> 4, lm = lane & 15;

    for (int tile = blockIdx.x; tile < ntile_cnt; tile += gridDim.x) {
        const int nbase = tile * 64 + wave * 16;
        int arow_i = nbase + lm;
        if (arow_i >= N) arow_i = N - 1;
        const float* arow = h + (size_t)arow_i * HD + g * 8;

        short8 afrag[4];
        #pragma unroll
        for (int kk = 0; kk < 4; ++kk) {
            f32x4 lo = *reinterpret_cast<const f32x4*>(arow + kk * 32);
            f32x4 hi = *reinterpret_cast<const f32x4*>(arow + kk * 32 + 4);
            afrag[kk] = pack8(lo, hi);
        }

        float pr[4][5];
        #pragma unroll
        for (int r = 0; r < 4; ++r)
            #pragma unroll
            for (int k = 0; k < 5; ++k) pr[r][k] = 0.f;

        #pragma unroll
        for (int nt = 0; nt < 8; ++nt) {
            f32x4 acc = {0.f, 0.f, 0.f, 0.f};
            #pragma unroll
            for (int kk = 0; kk < 4; ++kk) {
                short8 bfrag = *reinterpret_cast<const short8*>(&w1s[kk * 4 + g][nt * 16 + lm][0]);
                acc = __builtin_amdgcn_mfma_f32_16x16x32_bf16(afrag[kk], bfrag, acc, 0, 0, 0);
            }
            const int col = nt * 16 + lm;
            const float bb = b1s[col];
            #pragma unroll
            for (int r = 0; r < 4; ++r) {
                float s = fast_silu(acc[r] + bb);
                #pragma unroll
                for (int k = 0; k < 5; ++k) pr[r][k] += s * w2s[col * 5 + k];
            }
        }

        #pragma unroll
        for (int r = 0; r < 4; ++r)
            #pragma unroll
            for (int k = 0; k < 5; ++k) {
                float v = pr[r][k];
                v += __shfl_xor(v, 1); v += __shfl_xor(v, 2);
                v += __shfl_xor(v, 4); v += __shfl_xor(v, 8);
                pr[r][k] = v;
            }

        if (lm < 4) {
            const int n = nbase + g * 4 + lm;
            if (n < N) {
                float alpha[5];
                #pragma unroll
                for (int k = 0; k < 5; ++k) {
                    float a = lm == 0 ? pr[0][k] : lm == 1 ? pr[1][k] : lm == 2 ? pr[2][k] : pr[3][k];
                    alpha[k] = a + b2s[k];
                }
                const float* vp = vel + (size_t)n * 15;
                float o0 = 0.f, o1 = 0.f, o2 = 0.f;
                #pragma unroll
                for (int k = 0; k < 5; ++k) {
                    o0 += alpha[k] * vp[k * 3 + 0];
                    o1 += alpha[k] * vp[k * 3 + 1];
                    o2 += alpha[k] * vp[k * 3 + 2];
                }
                // ---- decode u64 fixed-point accumulator ----
                unsigned long long v = acc8[n];
                const int K  = (int)(v & 0xFFFF);
                const int f2 = (int)((v >> 16) & 0xFFFF);
                const int f1 = (int)((v >> 32) & 0xFFFF);
                const int f0 = (int)((v >> 48) & 0xFFFF);
                const int KB = K * 16384;
                int S2 = (((f2 - KB + 32768) & 0xFFFF)) - 32768;
                int C2 = (KB + S2 - f2) >> 16;
                int S1 = (((f1 - KB - C2 + 32768) & 0xFFFF)) - 32768;
                int C1 = (KB + S1 + C2 - f1) >> 16;
                int S0 = (((f0 - KB - C1 + 32768) & 0xFFFF)) - 32768;
                const float inv = 1.f / (32.f * (float)(K > 0 ? K : 1));
                float* op = out + (size_t)n * 3;
                op[0] = o0 + (float)S0 * inv;
                op[1] = o1 + (float)S1 * inv;
                op[2] = o2 + (float)S2 * inv;
            }
        }
    }
}

extern "C" void kernel_launch(void* const* d_in, const int* in_sizes, int n_in,
                              void* d_out, int out_size, void* d_ws, size_t ws_size,
                              hipStream_t stream) {
    const float* h     = (const float*)d_in[0];
    const float* m_ij  = (const float*)d_in[1];
    const float* x     = (const float*)d_in[2];
    const float* vel   = (const float*)d_in[3];
    const int*   ei    = (const int*)d_in[4];
    const float* ew_W1 = (const float*)d_in[5];
    const float* ew_b1 = (const float*)d_in[6];
    const float* ew_W2 = (const float*)d_in[7];
    const float* ew_b2 = (const float*)d_in[8];
    const float* vg_W1 = (const float*)d_in[9];
    const float* vg_b1 = (const float*)d_in[10];
    const float* vg_W2 = (const float*)d_in[11];
    const float* vg_b2 = (const float*)d_in[12];

    const int N = in_sizes[0] / HD;
    const int E = in_sizes[4] / 2;

    unsigned long long* acc8 = (unsigned long long*)d_ws;   // [N] u64
    const int nvec4 = (N * 2 + 3) / 4;
    zero_kernel<<<(nvec4 + 511) / 512, 512, 0, stream>>>((float*)d_ws, nvec4);

    const int etiles = (E + 127) / 128;                     // 128 edges / block
    const int egrid = etiles < 1024 ? etiles : 1024;        // one resident batch
    edge_kernel<<<egrid, 512, 0, stream>>>(m_ij, x, ei, ei + E,
                                           ew_W1, ew_b1, ew_W2, ew_b2,
                                           acc8, E, etiles);

    const int ntiles = (N + 63) / 64;
    node_kernel<<<ntiles, 256, 0, stream>>>(h, vel,
                                            vg_W1, vg_b1, vg_W2, vg_b2,
                                            acc8, (float*)d_out, N, ntiles);
}

// Round 20
// 248.170 us; speedup vs baseline: 2.8221x; 2.8221x over previous
//
#include <hip/hip_runtime.h>
#include <hip/hip_bf16.h>

#define HD 128

typedef __attribute__((ext_vector_type(8))) short short8;
typedef __attribute__((ext_vector_type(4))) float f32x4;
typedef __attribute__((ext_vector_type(4))) unsigned int u32x4;

// fast silu: v * rcp(1+exp(-v))
__device__ __forceinline__ float fast_silu(float v) {
    return v * __builtin_amdgcn_rcpf(1.f + __expf(-v));
}

// RNE f32 pair -> packed bf16x2 via HW cvt
__device__ __forceinline__ unsigned int pk2(float a, float b) {
    __hip_bfloat162 h = __float22bfloat162_rn(float2{a, b});
    unsigned int u;
    __builtin_memcpy(&u, &h, 4);
    return u;
}

__device__ __forceinline__ unsigned short f2bf(float f) {
    unsigned int u = __builtin_bit_cast(unsigned int, f);
    u += 0x7FFFu + ((u >> 16) & 1u);   // RNE
    return (unsigned short)(u >> 16);
}

// pack 8 f32 -> short8 of bf16 (RNE)
__device__ __forceinline__ short8 pack8(f32x4 lo, f32x4 hi) {
    u32x4 p;
    p[0] = pk2(lo[0], lo[1]);
    p[1] = pk2(lo[2], lo[3]);
    p[2] = pk2(hi[0], hi[1]);
    p[3] = pk2(hi[2], hi[3]);
    return __builtin_bit_cast(short8, p);
}

// fixed-point field: 16384 + rint(m*32), clamped, fits [0, 2^15)
__device__ __forceinline__ unsigned long long fpf(float m) {
    int r = (int)rintf(m * 32.f);
    r = r < -16000 ? -16000 : (r > 16000 ? 16000 : r);
    return (unsigned long long)(unsigned)(16384 + r);
}

// ---------------- zero workspace ----------------
__global__ __launch_bounds__(512) void zero_kernel(float* __restrict__ p, int nvec4) {
    int i = blockIdx.x * 512 + threadIdx.x;
    if (i < nvec4) reinterpret_cast<f32x4*>(p)[i] = f32x4{0.f, 0.f, 0.f, 0.f};
}

// Vectorized W1 staging into chunk-major LDS: w1s[c][n][j] = W1[(c*8+j)*128+n].
#define STAGE_W1_VEC(W1, w1s, nthr)                                          \
    for (int i = threadIdx.x; i < (HD * HD / 8); i += (nthr)) {              \
        const int kp = i >> 5, nq = i & 31;                                  \
        const int k0 = kp * 2, n0 = nq * 4;                                  \
        f32x4 ra = *reinterpret_cast<const f32x4*>(W1 + k0 * HD + n0);       \
        f32x4 rb = *reinterpret_cast<const f32x4*>(W1 + (k0 + 1) * HD + n0); \
        _Pragma("unroll")                                                    \
        for (int j = 0; j < 4; ++j) {                                        \
            unsigned int u = pk2(ra[j], rb[j]);                              \
            *reinterpret_cast<unsigned int*>(&w1s[k0 >> 3][n0 + j][k0 & 6]) = u; \
        }                                                                    \
    }

// ---------------- edge kernel (512 threads = 8 waves, one W1 copy) --------
// R14 schedule: x-issue -> ei-prefetch -> pack A -> GEMM+silu -> consume x
// -> next A-loads -> atomic (youngest vmem op). No launch-bounds min:
// natural VGPR (~100-128) = 4 waves/SIMD; any forced cap spills (R19).
__global__ __launch_bounds__(512) void edge_kernel(
    const float* __restrict__ m_ij, const float* __restrict__ x,
    const int* __restrict__ srci, const int* __restrict__ dsti,
    const float* __restrict__ W1, const float* __restrict__ b1,
    const float* __restrict__ W2, const float* __restrict__ b2,
    unsigned long long* __restrict__ acc8, int E, int ntile_cnt)
{
    __shared__ __align__(16) unsigned short w1s[16][HD][8];   // 32 KB
    __shared__ float b1s[HD], w2s[HD];
    const int tid = threadIdx.x;
    STAGE_W1_VEC(W1, w1s, 512)
    if (tid < HD) { b1s[tid] = b1[tid]; w2s[tid] = W2[tid]; }
    __syncthreads();

    const int lane = tid & 63, wave = tid >> 6;
    const int g = lane >> 4, lm = lane & 15;
    const float b2v = b2[0];
    const bool owner = (lm < 4);

    int tile = blockIdx.x;
    f32x4 araw[8];
    int sc = 0, dc = 0;
    if (tile < ntile_cnt) {
        int ar = tile * 128 + wave * 16 + lm;
        if (ar >= E) ar = E - 1;
        const float* p = m_ij + (size_t)ar * HD + g * 8;
        #pragma unroll
        for (int kk = 0; kk < 4; ++kk) {
            araw[2 * kk]     = *reinterpret_cast<const f32x4*>(p + kk * 32);
            araw[2 * kk + 1] = *reinterpret_cast<const f32x4*>(p + kk * 32 + 4);
        }
        if (owner) {
            int e = tile * 128 + wave * 16 + g * 4 + lm;
            if (e >= E) e = E - 1;
            sc = srci[e]; dc = dsti[e];
        }
    }

    while (tile < ntile_cnt) {
        const int next = tile + gridDim.x;
        const int ecur = tile * 128 + wave * 16 + g * 4 + lm;
        const bool valid = owner && (ecur < E);

        // (1) issue x-loads for CURRENT tile (addresses prefetched)
        float xs0 = 0.f, xs1 = 0.f, xs2 = 0.f, xd0 = 0.f, xd1 = 0.f, xd2 = 0.f;
        if (valid) {
            const float* xs = x + (size_t)sc * 3;
            const float* xd = x + (size_t)dc * 3;
            xs0 = xs[0]; xs1 = xs[1]; xs2 = xs[2];
            xd0 = xd[0]; xd1 = xd[1]; xd2 = xd[2];
        }
        unsigned long long* aptr = valid ? &acc8[dc] : nullptr;

        // (2) prefetch ei for NEXT tile
        int sn = 0, dn = 0;
        if (owner && next < ntile_cnt) {
            int e = next * 128 + wave * 16 + g * 4 + lm;
            if (e >= E) e = E - 1;
            sn = srci[e]; dn = dsti[e];
        }

        // (3) pack A fragments
        short8 afrag[4];
        #pragma unroll
        for (int kk = 0; kk < 4; ++kk)
            afrag[kk] = pack8(araw[2 * kk], araw[2 * kk + 1]);

        // (4) GEMM + fused second layer
        float pr0 = 0.f, pr1 = 0.f, pr2 = 0.f, pr3 = 0.f;
        #pragma unroll
        for (int nt = 0; nt < 8; ++nt) {
            f32x4 acc = {0.f, 0.f, 0.f, 0.f};
            #pragma unroll
            for (int kk = 0; kk < 4; ++kk) {
                short8 bfrag = *reinterpret_cast<const short8*>(&w1s[kk * 4 + g][nt * 16 + lm][0]);
                acc = __builtin_amdgcn_mfma_f32_16x16x32_bf16(afrag[kk], bfrag, acc, 0, 0, 0);
            }
            const int col = nt * 16 + lm;
            const float bb = b1s[col], wv = w2s[col];
            pr0 += fast_silu(acc[0] + bb) * wv;
            pr1 += fast_silu(acc[1] + bb) * wv;
            pr2 += fast_silu(acc[2] + bb) * wv;
            pr3 += fast_silu(acc[3] + bb) * wv;
        }
        pr0 += __shfl_xor(pr0, 1); pr0 += __shfl_xor(pr0, 2); pr0 += __shfl_xor(pr0, 4); pr0 += __shfl_xor(pr0, 8);
        pr1 += __shfl_xor(pr1, 1); pr1 += __shfl_xor(pr1, 2); pr1 += __shfl_xor(pr1, 4); pr1 += __shfl_xor(pr1, 8);
        pr2 += __shfl_xor(pr2, 1); pr2 += __shfl_xor(pr2, 2); pr2 += __shfl_xor(pr2, 4); pr2 += __shfl_xor(pr2, 8);
        pr3 += __shfl_xor(pr3, 1); pr3 += __shfl_xor(pr3, 2); pr3 += __shfl_xor(pr3, 4); pr3 += __shfl_xor(pr3, 8);

        // (5) consume x at end of compute phase, build payload
        unsigned long long addend = 0;
        if (valid) {
            float w = (lm == 0 ? pr0 : lm == 1 ? pr1 : lm == 2 ? pr2 : pr3) + b2v;
            addend = (fpf((xs0 - xd0) * w) << 48) | (fpf((xs1 - xd1) * w) << 32)
                   | (fpf((xs2 - xd2) * w) << 16) | 1ULL;
        }

        // (6) issue next tile's A-loads BEFORE the atomic
        if (next < ntile_cnt) {
            int ar = next * 128 + wave * 16 + lm;
            if (ar >= E) ar = E - 1;
            const float* p = m_ij + (size_t)ar * HD + g * 8;
            #pragma unroll
            for (int kk = 0; kk < 4; ++kk) {
                araw[2 * kk]     = *reinterpret_cast<const f32x4*>(p + kk * 32);
                araw[2 * kk + 1] = *reinterpret_cast<const f32x4*>(p + kk * 32 + 4);
            }
        }

        // (7) atomic last: youngest vmem op in flight
        if (aptr) atomicAdd(aptr, addend);

        sc = sn; dc = dn;
        tile = next;
    }
}

// ---------------- node kernel ----------------
__global__ __launch_bounds__(256) void node_kernel(
    const float* __restrict__ h, const float* __restrict__ vel,
    const float* __restrict__ W1, const float* __restrict__ b1,
    const float* __restrict__ W2, const float* __restrict__ b2,
    const unsigned long long* __restrict__ acc8,
    float* __restrict__ out, int N, int ntile_cnt)
{
    __shared__ __align__(16) unsigned short w1s[16][HD][8];
    __shared__ float b1s[HD], w2s[HD * 5], b2s[5];
    const int tid = threadIdx.x;
    STAGE_W1_VEC(W1, w1s, 256)
    if (tid < HD) b1s[tid] = b1[tid];
    for (int i = tid; i < HD * 5; i += 256) w2s[i] = W2[i];
    if (tid < 5) b2s[tid] = b2[tid];
    __syncthreads();

    const int lane = tid & 63, wave = tid >> 6;
    const int g = lane >> 4, lm = lane & 15;

    for (int tile = blockIdx.x; tile < ntile_cnt; tile += gridDim.x) {
        const int nbase = tile * 64 + wave * 16;
        int arow_i = nbase + lm;
        if (arow_i >= N) arow_i = N - 1;
        const float* arow = h + (size_t)arow_i * HD + g * 8;

        short8 afrag[4];
        #pragma unroll
        for (int kk = 0; kk < 4; ++kk) {
            f32x4 lo = *reinterpret_cast<const f32x4*>(arow + kk * 32);
            f32x4 hi = *reinterpret_cast<const f32x4*>(arow + kk * 32 + 4);
            afrag[kk] = pack8(lo, hi);
        }

        float pr[4][5];
        #pragma unroll
        for (int r = 0; r < 4; ++r)
            #pragma unroll
            for (int k = 0; k < 5; ++k) pr[r][k] = 0.f;

        #pragma unroll
        for (int nt = 0; nt < 8; ++nt) {
            f32x4 acc = {0.f, 0.f, 0.f, 0.f};
            #pragma unroll
            for (int kk = 0; kk < 4; ++kk) {
                short8 bfrag = *reinterpret_cast<const short8*>(&w1s[kk * 4 + g][nt * 16 + lm][0]);
                acc = __builtin_amdgcn_mfma_f32_16x16x32_bf16(afrag[kk], bfrag, acc, 0, 0, 0);
            }
            const int col = nt * 16 + lm;
            const float bb = b1s[col];
            #pragma unroll
            for (int r = 0; r < 4; ++r) {
                float s = fast_silu(acc[r] + bb);
                #pragma unroll
                for (int k = 0; k < 5; ++k) pr[r][k] += s * w2s[col * 5 + k];
            }
        }

        #pragma unroll
        for (int r = 0; r < 4; ++r)
            #pragma unroll
            for (int k = 0; k < 5; ++k) {
                float v = pr[r][k];
                v += __shfl_xor(v, 1); v += __shfl_xor(v, 2);
                v += __shfl_xor(v, 4); v += __shfl_xor(v, 8);
                pr[r][k] = v;
            }

        if (lm < 4) {
            const int n = nbase + g * 4 + lm;
            if (n < N) {
                float alpha[5];
                #pragma unroll
                for (int k = 0; k < 5; ++k) {
                    float a = lm == 0 ? pr[0][k] : lm == 1 ? pr[1][k] : lm == 2 ? pr[2][k] : pr[3][k];
                    alpha[k] = a + b2s[k];
                }
                const float* vp = vel + (size_t)n * 15;
                float o0 = 0.f, o1 = 0.f, o2 = 0.f;
                #pragma unroll
                for (int k = 0; k < 5; ++k) {
                    o0 += alpha[k] * vp[k * 3 + 0];
                    o1 += alpha[k] * vp[k * 3 + 1];
                    o2 += alpha[k] * vp[k * 3 + 2];
                }
                // ---- decode u64 fixed-point accumulator ----
                unsigned long long v = acc8[n];
                const int K  = (int)(v & 0xFFFF);
                const int f2 = (int)((v >> 16) & 0xFFFF);
                const int f1 = (int)((v >> 32) & 0xFFFF);
                const int f0 = (int)((v >> 48) & 0xFFFF);
                const int KB = K * 16384;
                int S2 = (((f2 - KB + 32768) & 0xFFFF)) - 32768;
                int C2 = (KB + S2 - f2) >> 16;
                int S1 = (((f1 - KB - C2 + 32768) & 0xFFFF)) - 32768;
                int C1 = (KB + S1 + C2 - f1) >> 16;
                int S0 = (((f0 - KB - C1 + 32768) & 0xFFFF)) - 32768;
                const float inv = 1.f / (32.f * (float)(K > 0 ? K : 1));
                float* op = out + (size_t)n * 3;
                op[0] = o0 + (float)S0 * inv;
                op[1] = o1 + (float)S1 * inv;
                op[2] = o2 + (float)S2 * inv;
            }
        }
    }
}

extern "C" void kernel_launch(void* const* d_in, const int* in_sizes, int n_in,
                              void* d_out, int out_size, void* d_ws, size_t ws_size,
                              hipStream_t stream) {
    const float* h     = (const float*)d_in[0];
    const float* m_ij  = (const float*)d_in[1];
    const float* x     = (const float*)d_in[2];
    const float* vel   = (const float*)d_in[3];
    const int*   ei    = (const int*)d_in[4];
    const float* ew_W1 = (const float*)d_in[5];
    const float* ew_b1 = (const float*)d_in[6];
    const float* ew_W2 = (const float*)d_in[7];
    const float* ew_b2 = (const float*)d_in[8];
    const float* vg_W1 = (const float*)d_in[9];
    const float* vg_b1 = (const float*)d_in[10];
    const float* vg_W2 = (const float*)d_in[11];
    const float* vg_b2 = (const float*)d_in[12];

    const int N = in_sizes[0] / HD;
    const int E = in_sizes[4] / 2;

    unsigned long long* acc8 = (unsigned long long*)d_ws;   // [N] u64
    const int nvec4 = (N * 2 + 3) / 4;
    zero_kernel<<<(nvec4 + 511) / 512, 512, 0, stream>>>((float*)d_ws, nvec4);

    const int etiles = (E + 127) / 128;                     // 128 edges / block
    const int egrid = etiles < 1024 ? etiles : 1024;        // one resident batch
    edge_kernel<<<egrid, 512, 0, stream>>>(m_ij, x, ei, ei + E,
                                           ew_W1, ew_b1, ew_W2, ew_b2,
                                           acc8, E, etiles);

    const int ntiles = (N + 63) / 64;
    node_kernel<<<ntiles, 256, 0, stream>>>(h, vel,
                                            vg_W1, vg_b1, vg_W2, vg_b2,
                                            acc8, (float*)d_out, N, ntiles);
}